// Round 9
// baseline (1147.655 us; speedup 1.0000x reference)
//
#include <hip/hip_runtime.h>

typedef __attribute__((ext_vector_type(8))) short short8;   // 8 bf16 (MFMA A/B frag)
typedef __attribute__((ext_vector_type(16))) float f32x16;  // MFMA C/D frag (32x32)

union FragU { unsigned u[4]; short8 s8; };

__device__ __forceinline__ unsigned cvt_pk_bf16(float lo, float hi) {
  unsigned r;
  asm("v_cvt_pk_bf16_f32 %0, %1, %2" : "=v"(r) : "v"(lo), "v"(hi));
  return r;
}
// v_permlane32_swap_b32 modifies BOTH registers:
//   a' = {a[0:31] | b[0:31]},  b' = {a[32:63] | b[32:63]}
__device__ __forceinline__ void perm32_swap(unsigned& a, unsigned& b) {
  asm volatile("v_permlane32_swap_b32 %0, %1" : "+v"(a), "+v"(b));
}
__device__ __forceinline__ float bf_lo(unsigned u) { return __uint_as_float(u << 16); }
__device__ __forceinline__ float bf_hi(unsigned u) { return __uint_as_float(u & 0xffff0000u); }
__device__ __forceinline__ unsigned short f2bf(float f) {
  union { float f; unsigned u; } v; v.f = f;
  unsigned r = v.u + 0x7FFFu + ((v.u >> 16) & 1u);   // RNE
  return (unsigned short)(r >> 16);
}
__device__ __forceinline__ float tanh_fast(float x) {
  float e = __expf(2.0f * x);
  float r = __builtin_amdgcn_rcpf(e + 1.0f);
  return 1.0f - 2.0f * r;
}
__device__ __forceinline__ f32x16 zero16() {
  f32x16 z;
  #pragma unroll
  for (int i = 0; i < 16; ++i) z[i] = 0.0f;
  return z;
}

// p (packed bf16, P-layout) -> 4 B-frags, destructive on p.
__device__ __forceinline__ void build_frags(unsigned p[16], FragU F[4]) {
  #pragma unroll
  for (int kt = 0; kt < 4; ++kt) {
    perm32_swap(p[4*kt+0], p[4*kt+2]);
    perm32_swap(p[4*kt+1], p[4*kt+3]);
    F[kt].u[0] = p[4*kt+0]; F[kt].u[1] = p[4*kt+1];
    F[kt].u[2] = p[4*kt+2]; F[kt].u[3] = p[4*kt+3];
  }
}

// weights come from LDS: w[2*kt+mt][lane] is the A-frag for k-tile kt, m-tile mt
__device__ __forceinline__ void matmulL(const short8 (*w)[64], int lane,
                                        short8 bA0, short8 bA1, short8 ones,
                                        const f32x16& z, const FragU F[4],
                                        f32x16& c0, f32x16& c1) {
  // rank-1 bias init: C = b ⊗ 1  (z stays zero; D != C)
  c0 = __builtin_amdgcn_mfma_f32_32x32x16_bf16(bA0, ones, z, 0, 0, 0);
  c1 = __builtin_amdgcn_mfma_f32_32x32x16_bf16(bA1, ones, z, 0, 0, 0);
  #pragma unroll
  for (int kt = 0; kt < 4; ++kt) {
    short8 w0 = w[2*kt+0][lane];
    short8 w1 = w[2*kt+1][lane];
    c0 = __builtin_amdgcn_mfma_f32_32x32x16_bf16(w0, F[kt].s8, c0, 0, 0, 0);
    c1 = __builtin_amdgcn_mfma_f32_32x32x16_bf16(w1, F[kt].s8, c1, 0, 0, 0);
  }
}

__device__ __forceinline__ void tanh_pack(unsigned p[16], const f32x16& c0, const f32x16& c1) {
  #pragma unroll
  for (int g = 0; g < 8; ++g) {
    const f32x16& c = (g < 4) ? c0 : c1;
    int rg = g & 3;
    p[2*g+0] = cvt_pk_bf16(tanh_fast(c[4*rg+0]), tanh_fast(c[4*rg+1]));
    p[2*g+1] = cvt_pk_bf16(tanh_fast(c[4*rg+2]), tanh_fast(c[4*rg+3]));
  }
}

__device__ __forceinline__ void ypack(unsigned p[16], const unsigned xb[16], float cc,
                                      const f32x16& k0, const f32x16& k1) {
  #pragma unroll
  for (int g = 0; g < 8; ++g) {
    const f32x16& k = (g < 4) ? k0 : k1;
    int rg = g & 3;
    float y0 = bf_lo(xb[2*g+0]) + cc * k[4*rg+0];
    float y1 = bf_hi(xb[2*g+0]) + cc * k[4*rg+1];
    float y2 = bf_lo(xb[2*g+1]) + cc * k[4*rg+2];
    float y3 = bf_hi(xb[2*g+1]) + cc * k[4*rg+3];
    p[2*g+0] = cvt_pk_bf16(y0, y1);
    p[2*g+1] = cvt_pk_bf16(y2, y3);
  }
}

__global__ __launch_bounds__(256, 3)
void ode_rk4_kernel(const float* __restrict__ x, const float* __restrict__ W1,
                    const float* __restrict__ b1, const float* __restrict__ W2,
                    const float* __restrict__ b2, float* __restrict__ out,
                    int nstrips)
{
  // frag-ordered weight store: [m*8 + kt*2 + mt][lane] ; 16 KB, conflict-free b128 reads
  __shared__ short8 wlds[16][64];

  const int tid  = threadIdx.x;
  const int lane = tid & 63;
  const int ln   = lane & 31;
  const int hl   = lane >> 5;
  const int wv   = tid >> 6;

  if (wv == 0) {
    #pragma unroll
    for (int f = 0; f < 8; ++f) {
      int kt = f >> 1, mt = f & 1;
      int c = ln + 32*mt, kb = 16*kt + 8*hl;
      FragU f1, f2;
      #pragma unroll
      for (int j = 0; j < 4; ++j) {
        f1.u[j] = cvt_pk_bf16(W1[(kb+2*j)*64 + c], W1[(kb+2*j+1)*64 + c]);
        f2.u[j] = cvt_pk_bf16(W2[(kb+2*j)*64 + c], W2[(kb+2*j+1)*64 + c]);
      }
      wlds[f    ][lane] = f1.s8;
      wlds[8 + f][lane] = f2.s8;
    }
  }

  // bias rank-1 frags + shared zero C (kept in regs; small)
  FragU onesF; onesF.u[0] = hl ? 0u : 0x3F80u; onesF.u[1] = onesF.u[2] = onesF.u[3] = 0u;
  short8 b1A[2], b2A[2];
  #pragma unroll
  for (int mt = 0; mt < 2; ++mt) {
    FragU fb1, fb2;
    fb1.u[0] = hl ? 0u : (unsigned)f2bf(b1[ln + 32*mt]);
    fb2.u[0] = hl ? 0u : (unsigned)f2bf(b2[ln + 32*mt]);
    fb1.u[1] = fb1.u[2] = fb1.u[3] = 0u;
    fb2.u[1] = fb2.u[2] = fb2.u[3] = 0u;
    b1A[mt] = fb1.s8; b2A[mt] = fb2.s8;
  }
  const f32x16 z = zero16();

  __syncthreads();

  const int gw  = gridDim.x * 4;
  int wid       = blockIdx.x * 4 + wv;
  const int lnoff = ln * 16 + hl;   // float4 index of this lane's first group

  for (int s = wid; s < nstrips; s += gw) {
    const float4* xs4 = (const float4*)x   + (size_t)s * 512;
    float4*       os4 = (float4*)out       + (size_t)s * 512;

    // ---- load x (8 x float4 per lane), pack to bf16 P-layout ----
    unsigned xb[16];
    #pragma unroll
    for (int g = 0; g < 8; ++g) {
      float4 v = xs4[lnoff + 8*(g>>2) + 2*(g&3)];
      xb[2*g+0] = cvt_pk_bf16(v.x, v.y);
      xb[2*g+1] = cvt_pk_bf16(v.z, v.w);
    }

    f32x16 acc0, acc1, ct0, ct1;
    FragU F[4];
    unsigned p[16];

    // ---- stage 1: k1 = f(x) ----
    #pragma unroll
    for (int i = 0; i < 16; ++i) p[i] = xb[i];
    build_frags(p, F);
    matmulL(&wlds[0], lane, b1A[0], b1A[1], onesF.s8, z, F, ct0, ct1);  // x@W1+b1
    tanh_pack(p, ct0, ct1);
    build_frags(p, F);
    matmulL(&wlds[8], lane, b2A[0], b2A[1], onesF.s8, z, F, ct0, ct1);  // k1
    acc0 = ct0; acc1 = ct1;

    // ---- stages 2..4 ----
    #pragma unroll
    for (int st = 1; st < 4; ++st) {
      const float cc = (st == 3) ? 1.0f : 0.5f;
      const float wc = (st == 3) ? 1.0f : 2.0f;
      ypack(p, xb, cc, ct0, ct1);              // y = x + cc*k_prev (bf16)
      build_frags(p, F);
      matmulL(&wlds[0], lane, b1A[0], b1A[1], onesF.s8, z, F, ct0, ct1); // y@W1+b1
      tanh_pack(p, ct0, ct1);
      build_frags(p, F);
      matmulL(&wlds[8], lane, b2A[0], b2A[1], onesF.s8, z, F, ct0, ct1); // k_st
      acc0 += wc * ct0; acc1 += wc * ct1;
    }

    // ---- out = x + acc/6 ----
    #pragma unroll
    for (int g = 0; g < 8; ++g) {
      const f32x16& a = (g < 4) ? acc0 : acc1;
      int rg = g & 3;
      float4 o;
      o.x = bf_lo(xb[2*g+0]) + (1.0f/6.0f) * a[4*rg+0];
      o.y = bf_hi(xb[2*g+0]) + (1.0f/6.0f) * a[4*rg+1];
      o.z = bf_lo(xb[2*g+1]) + (1.0f/6.0f) * a[4*rg+2];
      o.w = bf_hi(xb[2*g+1]) + (1.0f/6.0f) * a[4*rg+3];
      os4[lnoff + 8*(g>>2) + 2*(g&3)] = o;
    }
  }
}

extern "C" void kernel_launch(void* const* d_in, const int* in_sizes, int n_in,
                              void* d_out, int out_size, void* d_ws, size_t ws_size,
                              hipStream_t stream) {
  const float* x  = (const float*)d_in[0];
  const float* W1 = (const float*)d_in[1];
  const float* b1 = (const float*)d_in[2];
  const float* W2 = (const float*)d_in[3];
  const float* b2 = (const float*)d_in[4];
  float* out = (float*)d_out;
  int nstrips = in_sizes[0] / 2048;   // rows / 32
  // grid 768 = 3 blocks/CU resident (matches __launch_bounds__(256,3)) — steady occupancy
  ode_rk4_kernel<<<768, 256, 0, stream>>>(x, W1, b1, W2, b2, out, nstrips);
}